// Round 7
// baseline (691.617 us; speedup 1.0000x reference)
//
#include <hip/hip_runtime.h>
#include <math.h>

#define Hd 256
#define Wd 256
#define Cd 128
#define BIGV 1.0e9f

typedef float f32x4 __attribute__((ext_vector_type(4)));

static __device__ __forceinline__ float softplus_f(float x) {
    return fmaxf(x, 0.0f) + log1pf(expf(-fabsf(x)));
}

// uniform (SGPR) pointer hoist -> s_load for wave-uniform weight reads.
static __device__ __forceinline__ const float* uniform_cptr(const float* p) {
    unsigned long long u = (unsigned long long)p;
    unsigned lo = __builtin_amdgcn_readfirstlane((unsigned)u);
    unsigned hi = __builtin_amdgcn_readfirstlane((unsigned)(u >> 32));
    return (const float*)(((unsigned long long)hi << 32) | lo);
}

// ---- DPP helpers (gfx9/CDNA DPP controls; old = FLT_MAX = min identity) ----
#define FMAXBITS 0x7F7FFFFF
template<int CTRL, int RM>
static __device__ __forceinline__ float dpp_mv(float x) {
    return __int_as_float(__builtin_amdgcn_update_dpp(
        FMAXBITS, __float_as_int(x), CTRL, RM, 0xF, false));
}
template<int CTRL, int RM>
static __device__ __forceinline__ float dpp_min(float x) {
    return fminf(x, dpp_mv<CTRL, RM>(x));
}
// inclusive prefix-min across 64 lanes
static __device__ __forceinline__ float wave_prefmin(float x) {
    x = dpp_min<0x111, 0xF>(x);   // row_shr:1
    x = dpp_min<0x112, 0xF>(x);   // row_shr:2
    x = dpp_min<0x114, 0xF>(x);   // row_shr:4
    x = dpp_min<0x118, 0xF>(x);   // row_shr:8
    x = dpp_min<0x142, 0xA>(x);   // row_bcast15 -> rows 1,3
    x = dpp_min<0x143, 0xC>(x);   // row_bcast31 -> rows 2,3
    return x;
}

#define TILE 16
#define HPX 18
#define PXN 324
#define SP  325
#define CHUNK 32

// ---------------------------------------------------------------------------
// Kernel 1: COST-ONLY per-pixel work (proven R12 version, unchanged).
// ---------------------------------------------------------------------------
__global__ __launch_bounds__(256) void k_cost(
    const float* __restrict__ feat,
    float* __restrict__ out, float* __restrict__ costP)
{
    __shared__ float stage[CHUNK * SP];
    __shared__ float normL[PXN];

    const int t  = threadIdx.x;
    const int r0 = blockIdx.y * TILE;
    const int c0 = blockIdx.x * TILE;

    const int lr = t >> 4, lc = t & 15;
    const int r = r0 + lr, c = c0 + lc;
    const int px0 = (lr + 1) * HPX + (lc + 1);

    float dotv[8];
#pragma unroll
    for (int j = 0; j < 8; ++j) dotv[j] = 0.0f;

    for (int ch0 = 0; ch0 < Cd; ch0 += CHUNK) {
        __syncthreads();
        for (int i = t; i < PXN * 8; i += 256) {
            int px = i >> 3, f4 = i & 7;
            int pr = px / HPX;
            int pc = px - pr * HPX;
            int gr = r0 - 1 + pr, gc = c0 - 1 + pc;
            float4 v = make_float4(0.f, 0.f, 0.f, 0.f);
            if ((unsigned)gr < Hd && (unsigned)gc < Wd) {
                v = *reinterpret_cast<const float4*>(
                        &feat[(((gr << 8) + gc) * Cd) + ch0 + (f4 << 2)]);
            }
            int chb = f4 << 2;
            stage[(chb + 0) * SP + px] = v.x;
            stage[(chb + 1) * SP + px] = v.y;
            stage[(chb + 2) * SP + px] = v.z;
            stage[(chb + 3) * SP + px] = v.w;
        }
        __syncthreads();
        for (int px = t; px < PXN; px += 256) {
            float s = 0.0f;
#pragma unroll
            for (int ch = 0; ch < CHUNK; ++ch) {
                float v = stage[ch * SP + px];
                s = fmaf(v, v, s);
            }
            if (ch0 == 0) normL[px] = s; else normL[px] += s;
        }
        for (int ch = 0; ch < CHUNK; ++ch) {
            const float* pl = stage + ch * SP + px0;
            float x  = pl[0];
            float n0 = pl[-HPX - 1], n1 = pl[-HPX], n2 = pl[-HPX + 1];
            float n3 = pl[-1],                      n4 = pl[1];
            float n5 = pl[HPX - 1],  n6 = pl[HPX],  n7 = pl[HPX + 1];

            dotv[0] = fmaf(x, n0, dotv[0]);
            dotv[1] = fmaf(x, n1, dotv[1]);
            dotv[2] = fmaf(x, n2, dotv[2]);
            dotv[3] = fmaf(x, n3, dotv[3]);
            dotv[4] = fmaf(x, n4, dotv[4]);
            dotv[5] = fmaf(x, n5, dotv[5]);
            dotv[6] = fmaf(x, n6, dotv[6]);
            dotv[7] = fmaf(x, n7, dotv[7]);
        }
    }
    __syncthreads();

    const int p = (r << 8) + c;
    float np = fmaxf(sqrtf(normL[px0]), 1e-12f);
    const int drr[8] = {-1,-1,-1, 0, 0, 1, 1, 1};
    const int dcc[8] = {-1, 0, 1,-1, 1,-1, 0, 1};
    const int nof[8] = {-HPX-1,-HPX,-HPX+1,-1,1,HPX-1,HPX,HPX+1};
#pragma unroll
    for (int j = 0; j < 8; ++j) {
        int nr = r + drr[j], nc = c + dcc[j];
        float cj;
        if ((unsigned)nr < Hd && (unsigned)nc < Wd) {
            float nn = fmaxf(sqrtf(normL[px0 + nof[j]]), 1e-12f);
            cj = 1.0f - dotv[j] / (np * nn);
        } else {
            cj = BIGV;
        }
        costP[(j << 16) + p] = cj;
        out[p * 10 + 1 + j]  = cj;
    }
}

// ---------------------------------------------------------------------------
// Kernel 2: per-row exclusive prefix sums of horizontal edge costs (unchanged).
// ---------------------------------------------------------------------------
__global__ __launch_bounds__(64) void k_scan(
    const float* __restrict__ costP, float* __restrict__ PR, float* __restrict__ PRm)
{
    const int r = blockIdx.x;
    const int l = threadIdx.x;
    const int base = (r << 8) + (l << 2);

    {
        const float4 c4 = *(const float4*)&costP[(4 << 16) + base];
        float a0 = c4.x, a1 = a0 + c4.y, a2 = a1 + c4.z, a3 = a2 + c4.w;
        float ta = a3;
#pragma unroll
        for (int o = 1; o < 64; o <<= 1) {
            float xa = __shfl_up(ta, o, 64);
            if (l >= o) ta += xa;
        }
        float ea = __shfl_up(ta, 1, 64); if (l == 0) ea = 0.0f;
        float4 P; P.x = ea; P.y = ea + a0; P.z = ea + a1; P.w = ea + a2;
        *(float4*)&PR[base] = P;
    }
    {
        const float4 m = *(const float4*)&costP[(3 << 16) + (r << 8) + (252 - (l << 2))];
        float w0 = m.w, w1_ = m.z, w2_ = m.y, w3 = m.x;
        float a0 = w0, a1 = a0 + w1_, a2 = a1 + w2_, a3 = a2 + w3;
        float ta = a3;
#pragma unroll
        for (int o = 1; o < 64; o <<= 1) {
            float xa = __shfl_up(ta, o, 64);
            if (l >= o) ta += xa;
        }
        float ea = __shfl_up(ta, 1, 64); if (l == 0) ea = 0.0f;
        float4 P; P.x = ea; P.y = ea + a0; P.z = ea + a1; P.w = ea + a2;
        *(float4*)&PRm[base] = P;
    }
}

// ---------------------------------------------------------------------------
// R5-EXACT sweep core (proven 61us): volatile-asm pipelined, SDEPTH=4.
// R6 lesson: SDEPTH=8 spilled (VGPR 76 < 128 buffers) -> scratch on the DP
// critical path. DEPTH=4 fits in registers (88 VGPR) -- do not deepen.
// ---------------------------------------------------------------------------
#define SDEPTH 4

template<int VD> static __device__ __forceinline__ int row_of(int ii) {
    int c = ii > 255 ? 255 : ii;
    return VD ? c : 255 - c;
}
template<int VD> static __device__ __forceinline__ int rowp_of(int ii) {
    int c = ii - 1; c = c < 0 ? 0 : (c > 255 ? 255 : c);
    return VD ? c : 255 - c;
}

template<int M, int VD>
static __device__ __forceinline__ void sweep_run(
    int l, int sr, int sc,
    const float* __restrict__ PRu,
    const float* __restrict__ cInP,
    const float* __restrict__ cStP,
    const float* __restrict__ cDeP,
    float* __restrict__ O)
{
    const int lane4 = l << 2;
    f32x4 sv = {BIGV, BIGV, BIGV, BIGV};
    {
        int kk = sc - lane4;
        if (kk == 0) sv[0] = 0.0f;
        if (kk == 1) sv[1] = 0.0f;
        if (kk == 2) sv[2] = 0.0f;
        if (kk == 3) sv[3] = 0.0f;
    }
    const int iStart = VD ? sr : 255 - sr;

    f32x4 bPR[SDEPTH], bI[SDEPTH], bS[SDEPTH], bD[SDEPTH];
    f32x4 Dp = {BIGV, BIGV, BIGV, BIGV};

#define KXc(v) (M ? (v)[3] : (v)[0])
#define KYc(v) (M ? (v)[2] : (v)[1])
#define KZc(v) (M ? (v)[1] : (v)[2])
#define KWc(v) (M ? (v)[0] : (v)[3])

#define SW_ISSUE(slot, jn) do {                                               \
        int rP_ = row_of<VD>(jn), rC_ = rowp_of<VD>(jn);                      \
        int voffP_ = ((rP_ << 8) + lane4) << 2;                               \
        int voffC_ = (M ? ((rC_ << 8) + 252 - lane4)                          \
                        : ((rC_ << 8) + lane4)) << 2;                         \
        asm volatile("global_load_dwordx4 %0, %1, %2"                         \
                     : "=v"(bPR[slot]) : "v"(voffP_), "s"(PRu));              \
        asm volatile("global_load_dwordx4 %0, %1, %2"                         \
                     : "=v"(bI[slot])  : "v"(voffC_), "s"(cInP));             \
        asm volatile("global_load_dwordx4 %0, %1, %2"                         \
                     : "=v"(bS[slot])  : "v"(voffC_), "s"(cStP));             \
        asm volatile("global_load_dwordx4 %0, %1, %2"                         \
                     : "=v"(bD[slot])  : "v"(voffC_), "s"(cDeP));             \
    } while (0)

#define SW_WAIT(n) do {                                                       \
        asm volatile("s_waitcnt vmcnt(" #n ")");                              \
        __builtin_amdgcn_sched_barrier(0);                                    \
    } while (0)

#define SW_BODY(slot, ivar) do {                                              \
        const int i__ = (ivar);                                               \
        const int r__ = VD ? i__ : 255 - i__;                                 \
        f32x4 PRc = bPR[slot];                                                \
        float tS0 = Dp[0] + KXc(bS[slot]), tS1 = Dp[1] + KYc(bS[slot]);       \
        float tS2 = Dp[2] + KZc(bS[slot]), tS3 = Dp[3] + KWc(bS[slot]);       \
        float tI0 = Dp[0] + KXc(bI[slot]), tI1 = Dp[1] + KYc(bI[slot]);       \
        float tI2 = Dp[2] + KZc(bI[slot]), tI3 = Dp[3] + KWc(bI[slot]);       \
        float tD0 = Dp[0] + KXc(bD[slot]), tD1 = Dp[1] + KYc(bD[slot]);       \
        float tD2 = Dp[2] + KZc(bD[slot]), tD3 = Dp[3] + KWc(bD[slot]);       \
        float tIm = dpp_mv<0x138, 0xF>(tI3);   /* wave_shr1 */                \
        float tDn = dpp_mv<0x130, 0xF>(tD0);   /* wave_shl1 */                \
        f32x4 cand;                                                           \
        cand[0] = fminf(tS0, fminf(tIm, tD1));                                \
        cand[1] = fminf(tS1, fminf(tI0, tD2));                                \
        cand[2] = fminf(tS2, fminf(tI1, tD3));                                \
        cand[3] = fminf(tS3, fminf(tI2, tDn));                                \
        if (i__ == iStart) {                                                  \
            cand[0] = fminf(cand[0], sv[0]); cand[1] = fminf(cand[1], sv[1]); \
            cand[2] = fminf(cand[2], sv[2]); cand[3] = fminf(cand[3], sv[3]); \
        }                                                                     \
        float z0 = cand[0] - PRc[0];                                          \
        float z1 = fminf(cand[1] - PRc[1], z0);                               \
        float z2 = fminf(cand[2] - PRc[2], z1);                               \
        float z3 = fminf(cand[3] - PRc[3], z2);                               \
        float w__ = wave_prefmin(z3);                                         \
        float e__ = dpp_mv<0x138, 0xF>(w__);   /* exclusive prefix */         \
        f32x4 D__;                                                            \
        D__[0] = PRc[0] + fminf(z0, e__);                                     \
        D__[1] = PRc[1] + fminf(z1, e__);                                     \
        D__[2] = PRc[2] + fminf(z2, e__);                                     \
        D__[3] = PRc[3] + fminf(z3, e__);                                     \
        int voffO_ = ((r__ << 8) + lane4) << 2;                               \
        asm volatile("global_store_dwordx4 %0, %1, %2"                        \
                     :: "v"(voffO_), "v"(D__), "s"(O));                       \
        Dp = D__;                                                             \
        SW_ISSUE(slot, i__ + SDEPTH);                                         \
    } while (0)

    // prologue: issue groups for rows 0..3 (16 loads in flight)
#pragma unroll
    for (int k = 0; k < SDEPTH; ++k) SW_ISSUE(k, k);

    // peeled rows 0..3 (exact FIFO counts), then steady state vmcnt(15)
    SW_WAIT(12); SW_BODY(0, 0);
    SW_WAIT(13); SW_BODY(1, 1);
    SW_WAIT(14); SW_BODY(2, 2);
    SW_WAIT(15); SW_BODY(3, 3);
    for (int ib = SDEPTH; ib < 256; ib += SDEPTH) {
        SW_WAIT(15); SW_BODY(0, ib + 0);
        SW_WAIT(15); SW_BODY(1, ib + 1);
        SW_WAIT(15); SW_BODY(2, ib + 2);
        SW_WAIT(15); SW_BODY(3, ib + 3);
    }
    asm volatile("s_waitcnt vmcnt(0)");   // drain stores before endpgm

#undef SW_ISSUE
#undef SW_WAIT
#undef SW_BODY
#undef KXc
#undef KYc
#undef KZc
#undef KWc
}

// ---------------------------------------------------------------------------
// Kernel 3 (R18): 512-thread blocks.
//   blocks 0..3   = R5-exact DEPTH-4 asm sweeps (lane 0..63; rest exit).
//   blocks 4..259 = heuristic, CHANNEL-SPLIT 2 ways: half0 (t<256) does
//     ch 0..63 (+abs), half1 does ch 64..127 (+var), each staging its own
//     channels (16-ch chunks). One-time LDS combine (34 floats/px, aliasing
//     the dead stage buffer) merges gm/var/abs/hv; half0 runs the epilogue.
//   Effect: 8 waves/CU = 2 waves/SIMD (was 1) with per-wave work halved --
//   attacks the latency-exposure that capped the heuristic at ~60us.
// ---------------------------------------------------------------------------
#define HCH   16                    // staging chunk (channels) per half
__global__ __launch_bounds__(512) void k_main(
    const float* __restrict__ feat,
    const float* __restrict__ w1, const float* __restrict__ b1,
    const float* __restrict__ w2, const float* __restrict__ b2,
    const float* __restrict__ dlt, const float* __restrict__ gmm,
    const float* __restrict__ bta, const int* __restrict__ endn,
    const float* __restrict__ costP, const float* __restrict__ PR,
    const float* __restrict__ PRm, const int* __restrict__ startn,
    float* __restrict__ out, float* __restrict__ distQ)
{
    if (blockIdx.x < 4) {
        const int l = threadIdx.x;
        if (l >= 64) return;
        __builtin_amdgcn_s_setprio(1);     // latency-critical chain wins issue
        const int sw  = blockIdx.x;
        const int sr  = startn[0];
        const int sc0 = startn[1];
        float* O = distQ + (sw << 16);
        if (sw == 0)
            sweep_run<0,1>(l, sr, sc0,       PR,  costP + (7<<16), costP + (6<<16), costP + (5<<16), O);
        else if (sw == 1)
            sweep_run<1,1>(l, sr, 255 - sc0, PRm, costP + (5<<16), costP + (6<<16), costP + (7<<16), O);
        else if (sw == 2)
            sweep_run<0,0>(l, sr, sc0,       PR,  costP + (2<<16), costP + (1<<16), costP + (0<<16), O);
        else
            sweep_run<1,0>(l, sr, 255 - sc0, PRm, costP + (0<<16), costP + (1<<16), costP + (2<<16), O);
        return;
    }

    // ================= HEURISTIC PATH: 2-way channel split =================
    __shared__ float stage[2 * HCH * SP];   // 41.6 KB; reused as combine buf
    __shared__ float endfL[64];
    __shared__ float vendL[64];
    __shared__ float vendS;

    const int t    = threadIdx.x;
    const int px   = t & 255;               // pixel id within tile
    const int half = t >> 8;                // 0: ch 0..63 (+abs), 1: 64..127 (+var)
    const int b    = blockIdx.x - 4;
    const int r0   = (b >> 4) * TILE;
    const int c0   = (b & 15) * TILE;
    float* __restrict__ stageH = stage + half * (HCH * SP);

    const float* __restrict__ w1u = uniform_cptr(w1);

    const int er = endn[0], ec = endn[1];
    if (t < 64) {
        endfL[t] = feat[(er * Wd + ec) * Cd + t];
        float s1 = 0.0f, s2 = 0.0f;
#pragma unroll
        for (int dr = -1; dr <= 1; ++dr)
#pragma unroll
            for (int dc = -1; dc <= 1; ++dc) {
                int gr = er + dr, gc = ec + dc;
                if ((unsigned)gr < Hd && (unsigned)gc < Wd) {
                    float x = feat[((gr << 8) + gc) * Cd + 64 + t];
                    s1 += x; s2 = fmaf(x, x, s2);
                }
            }
        float m = s1 * (1.0f / 9.0f);
        vendL[t] = s2 * (1.0f / 9.0f) - m * m;
    }

    const int lr = px >> 4, lc = px & 15;
    const int r = r0 + lr, c = c0 + lc;
    const int px0 = (lr + 1) * HPX + (lc + 1);

    float4 hv[8];
#pragma unroll
    for (int j = 0; j < 8; ++j) hv[j] = make_float4(0.f, 0.f, 0.f, 0.f);
    float gm_acc = 0.0f, va_acc = 0.0f;     // va = abs (half0) / var (half1)

    for (int cc = 0; cc < 64 / HCH; ++cc) {
        const int ch0 = (half << 6) + (cc << 4);   // this half's chunk base
        __syncthreads();
        // stage 324 px x 16 ch for this half (each half's 256 threads)
        for (int i = px; i < PXN * 4; i += 256) {
            int pxi = i >> 2, f4 = i & 3;
            int pr = pxi / HPX;
            int pc = pxi - pr * HPX;
            int gr = r0 - 1 + pr, gc = c0 - 1 + pc;
            float4 v = make_float4(0.f, 0.f, 0.f, 0.f);
            if ((unsigned)gr < Hd && (unsigned)gc < Wd) {
                v = *reinterpret_cast<const float4*>(
                        &feat[(((gr << 8) + gc) * Cd) + ch0 + (f4 << 2)]);
            }
            int chb = f4 << 2;
            stageH[(chb + 0) * SP + pxi] = v.x;
            stageH[(chb + 1) * SP + pxi] = v.y;
            stageH[(chb + 2) * SP + pxi] = v.z;
            stageH[(chb + 3) * SP + pxi] = v.w;
        }
        __syncthreads();
        for (int ch = 0; ch < HCH; ++ch) {
            const float* pl = stageH + ch * SP + px0;
            float x  = pl[0];
            float n0 = pl[-HPX - 1], n1 = pl[-HPX], n2 = pl[-HPX + 1];
            float n3 = pl[-1],                      n4 = pl[1];
            float n5 = pl[HPX - 1],  n6 = pl[HPX],  n7 = pl[HPX + 1];

            float gx = (n2 + 2.f * n4 + n7) - (n0 + 2.f * n3 + n5);
            float gy = (n5 + 2.f * n6 + n7) - (n0 + 2.f * n1 + n2);
            gm_acc += sqrtf(gx * gx + gy * gy);

            if (half) {   // ch>=64: local variance
                float s1 = x + n0 + n1 + n2 + n3 + n4 + n5 + n6 + n7;
                float s2 = x*x + n0*n0 + n1*n1 + n2*n2 + n3*n3 + n4*n4
                         + n5*n5 + n6*n6 + n7*n7;
                float m = s1 * (1.0f / 9.0f);
                va_acc += s2 * (1.0f / 9.0f) - m * m;
            } else {      // ch<64: absorption distance^2
                float dlf = x - endfL[ch0 + ch];
                va_acc = fmaf(dlf, dlf, va_acc);
            }

            // wave-uniform weight row -> scalar loads
            const float* __restrict__ wr = w1u + ((ch0 + ch) << 5);
#pragma unroll
            for (int j4 = 0; j4 < 8; ++j4) {
                hv[j4].x = fmaf(x, wr[(j4 << 2) + 0], hv[j4].x);
                hv[j4].y = fmaf(x, wr[(j4 << 2) + 1], hv[j4].y);
                hv[j4].z = fmaf(x, wr[(j4 << 2) + 2], hv[j4].z);
                hv[j4].w = fmaf(x, wr[(j4 << 2) + 3], hv[j4].w);
            }
        }
    }
    __syncthreads();   // stage dead -> reuse as combine buffer

    // half1 publishes partials (34 floats/px, stride-256 = conflict-free);
    // wave0 (t<64) reduces vend in parallel.
    if (half) {
        stage[0 * 256 + px] = gm_acc;
        stage[1 * 256 + px] = va_acc;      // var
#pragma unroll
        for (int j4 = 0; j4 < 8; ++j4) {
            stage[(2 + (j4 << 2) + 0) * 256 + px] = hv[j4].x;
            stage[(3 + (j4 << 2) + 0) * 256 + px] = hv[j4].y;
            stage[(4 + (j4 << 2) + 0) * 256 + px] = hv[j4].z;
            stage[(5 + (j4 << 2) + 0) * 256 + px] = hv[j4].w;
        }
    }
    if (t < 64) {
        float v = vendL[t];
#pragma unroll
        for (int o = 32; o > 0; o >>= 1) v += __shfl_down(v, o, 64);
        if (t == 0) vendS = v;
    }
    __syncthreads();
    if (half) return;

    const float vend = vendS;
    gm_acc += stage[0 * 256 + px];
    const float var_acc = stage[1 * 256 + px];
    const float abs_acc = va_acc;
#pragma unroll
    for (int j4 = 0; j4 < 8; ++j4) {
        hv[j4].x += stage[(2 + (j4 << 2) + 0) * 256 + px];
        hv[j4].y += stage[(3 + (j4 << 2) + 0) * 256 + px];
        hv[j4].z += stage[(4 + (j4 << 2) + 0) * 256 + px];
        hv[j4].w += stage[(5 + (j4 << 2) + 0) * 256 + px];
    }

    const int p = (r << 8) + c;
    float geo  = gm_acc * (1.0f / 128.0f);
    float absp = sqrtf(abs_acc);
    float o = b2[0];
#pragma unroll
    for (int j4 = 0; j4 < 8; ++j4) {
#pragma unroll
        for (int cci = 0; cci < 4; ++cci) {
            int j = (j4 << 2) + cci;
            float hj = fmaxf(((const float*)&hv[j4])[cci] + b1[j], 0.0f);
            o = fmaf(hj, w2[j], o);
        }
    }
    float omg = 1.0f / (1.0f + expf(-o));
    float dS = softplus_f(dlt[0]);
    float gS = softplus_f(gmm[0]);
    float bS = softplus_f(bta[0]);
    float heur = dS * geo + omg * gS * (vend - var_acc)
               + (1.0f - omg) * bS * absp;
    out[p * 10] = fmaxf(heur, 0.0f);
}

// ---------------------------------------------------------------------------
// Kernel 4: merge the 4 quadrant planes (un-mirroring planes 1,3) -> out ch 9
// ---------------------------------------------------------------------------
__global__ __launch_bounds__(256) void k_merge(
    const float* __restrict__ distQ, float* __restrict__ out)
{
    int p  = blockIdx.x * 256 + threadIdx.x;
    int pm = (p & ~255) + (255 - (p & 255));
    float v = fminf(fminf(distQ[p],           distQ[(2 << 16) + p]),
                    fminf(distQ[(1 << 16) + pm], distQ[(3 << 16) + pm]));
    out[p * 10 + 9] = fminf(v, BIGV);
}

// ---------------------------------------------------------------------------
extern "C" void kernel_launch(void* const* d_in, const int* in_sizes, int n_in,
                              void* d_out, int out_size, void* d_ws, size_t ws_size,
                              hipStream_t stream)
{
    const float* feat  = (const float*)d_in[0];
    const float* dlt   = (const float*)d_in[1];
    const float* gmm   = (const float*)d_in[2];
    const float* bta   = (const float*)d_in[3];
    const float* w1    = (const float*)d_in[4];
    const float* b1    = (const float*)d_in[5];
    const float* w2    = (const float*)d_in[6];
    const float* b2    = (const float*)d_in[7];
    const int*   startn= (const int*)d_in[8];
    const int*   endn  = (const int*)d_in[9];
    float* out = (float*)d_out;
    float* ws  = (float*)d_ws;

    float* costP = ws;                   // 8 planes
    float* PR    = ws + 8  * 65536;
    float* PRm   = ws + 9  * 65536;
    float* distQ = ws + 10 * 65536;      // 4 quadrant planes

    dim3 g16(16, 16);
    k_cost<<<g16, 256, 0, stream>>>(feat, out, costP);
    k_scan<<<256, 64, 0, stream>>>(costP, PR, PRm);
    k_main<<<260, 512, 0, stream>>>(feat, w1, b1, w2, b2, dlt, gmm, bta, endn,
                                    costP, PR, PRm, startn, out, distQ);
    k_merge<<<256, 256, 0, stream>>>(distQ, out);
}

// Round 8
// 168.379 us; speedup vs baseline: 4.1075x; 4.1075x over previous
//
#include <hip/hip_runtime.h>
#include <math.h>

#define Hd 256
#define Wd 256
#define Cd 128
#define BIGV 1.0e9f

typedef float f32x4 __attribute__((ext_vector_type(4)));

static __device__ __forceinline__ float softplus_f(float x) {
    return fmaxf(x, 0.0f) + log1pf(expf(-fabsf(x)));
}

// ---- DPP helpers (gfx9/CDNA DPP controls; old = FLT_MAX = min identity) ----
#define FMAXBITS 0x7F7FFFFF
template<int CTRL, int RM>
static __device__ __forceinline__ float dpp_mv(float x) {
    return __int_as_float(__builtin_amdgcn_update_dpp(
        FMAXBITS, __float_as_int(x), CTRL, RM, 0xF, false));
}
template<int CTRL, int RM>
static __device__ __forceinline__ float dpp_min(float x) {
    return fminf(x, dpp_mv<CTRL, RM>(x));
}
// inclusive prefix-min across 64 lanes
static __device__ __forceinline__ float wave_prefmin(float x) {
    x = dpp_min<0x111, 0xF>(x);   // row_shr:1
    x = dpp_min<0x112, 0xF>(x);   // row_shr:2
    x = dpp_min<0x114, 0xF>(x);   // row_shr:4
    x = dpp_min<0x118, 0xF>(x);   // row_shr:8
    x = dpp_min<0x142, 0xA>(x);   // row_bcast15 -> rows 1,3
    x = dpp_min<0x143, 0xC>(x);   // row_bcast31 -> rows 2,3
    return x;
}

#define TILE 16
#define HPX 18
#define PXN 324
#define SP  325
#define CHUNK 32

// ---------------------------------------------------------------------------
// Kernel 1: COST-ONLY per-pixel work (proven R12 version, unchanged).
// ---------------------------------------------------------------------------
__global__ __launch_bounds__(256) void k_cost(
    const float* __restrict__ feat,
    float* __restrict__ out, float* __restrict__ costP)
{
    __shared__ float stage[CHUNK * SP];
    __shared__ float normL[PXN];

    const int t  = threadIdx.x;
    const int r0 = blockIdx.y * TILE;
    const int c0 = blockIdx.x * TILE;

    const int lr = t >> 4, lc = t & 15;
    const int r = r0 + lr, c = c0 + lc;
    const int px0 = (lr + 1) * HPX + (lc + 1);

    float dotv[8];
#pragma unroll
    for (int j = 0; j < 8; ++j) dotv[j] = 0.0f;

    for (int ch0 = 0; ch0 < Cd; ch0 += CHUNK) {
        __syncthreads();
        for (int i = t; i < PXN * 8; i += 256) {
            int px = i >> 3, f4 = i & 7;
            int pr = px / HPX;
            int pc = px - pr * HPX;
            int gr = r0 - 1 + pr, gc = c0 - 1 + pc;
            float4 v = make_float4(0.f, 0.f, 0.f, 0.f);
            if ((unsigned)gr < Hd && (unsigned)gc < Wd) {
                v = *reinterpret_cast<const float4*>(
                        &feat[(((gr << 8) + gc) * Cd) + ch0 + (f4 << 2)]);
            }
            int chb = f4 << 2;
            stage[(chb + 0) * SP + px] = v.x;
            stage[(chb + 1) * SP + px] = v.y;
            stage[(chb + 2) * SP + px] = v.z;
            stage[(chb + 3) * SP + px] = v.w;
        }
        __syncthreads();
        for (int px = t; px < PXN; px += 256) {
            float s = 0.0f;
#pragma unroll
            for (int ch = 0; ch < CHUNK; ++ch) {
                float v = stage[ch * SP + px];
                s = fmaf(v, v, s);
            }
            if (ch0 == 0) normL[px] = s; else normL[px] += s;
        }
        for (int ch = 0; ch < CHUNK; ++ch) {
            const float* pl = stage + ch * SP + px0;
            float x  = pl[0];
            float n0 = pl[-HPX - 1], n1 = pl[-HPX], n2 = pl[-HPX + 1];
            float n3 = pl[-1],                      n4 = pl[1];
            float n5 = pl[HPX - 1],  n6 = pl[HPX],  n7 = pl[HPX + 1];

            dotv[0] = fmaf(x, n0, dotv[0]);
            dotv[1] = fmaf(x, n1, dotv[1]);
            dotv[2] = fmaf(x, n2, dotv[2]);
            dotv[3] = fmaf(x, n3, dotv[3]);
            dotv[4] = fmaf(x, n4, dotv[4]);
            dotv[5] = fmaf(x, n5, dotv[5]);
            dotv[6] = fmaf(x, n6, dotv[6]);
            dotv[7] = fmaf(x, n7, dotv[7]);
        }
    }
    __syncthreads();

    const int p = (r << 8) + c;
    float np = fmaxf(sqrtf(normL[px0]), 1e-12f);
    const int drr[8] = {-1,-1,-1, 0, 0, 1, 1, 1};
    const int dcc[8] = {-1, 0, 1,-1, 1,-1, 0, 1};
    const int nof[8] = {-HPX-1,-HPX,-HPX+1,-1,1,HPX-1,HPX,HPX+1};
#pragma unroll
    for (int j = 0; j < 8; ++j) {
        int nr = r + drr[j], nc = c + dcc[j];
        float cj;
        if ((unsigned)nr < Hd && (unsigned)nc < Wd) {
            float nn = fmaxf(sqrtf(normL[px0 + nof[j]]), 1e-12f);
            cj = 1.0f - dotv[j] / (np * nn);
        } else {
            cj = BIGV;
        }
        costP[(j << 16) + p] = cj;
        out[p * 10 + 1 + j]  = cj;
    }
}

// ---------------------------------------------------------------------------
// Kernel 2: per-row exclusive prefix sums of horizontal edge costs (unchanged).
// ---------------------------------------------------------------------------
__global__ __launch_bounds__(64) void k_scan(
    const float* __restrict__ costP, float* __restrict__ PR, float* __restrict__ PRm)
{
    const int r = blockIdx.x;
    const int l = threadIdx.x;
    const int base = (r << 8) + (l << 2);

    {
        const float4 c4 = *(const float4*)&costP[(4 << 16) + base];
        float a0 = c4.x, a1 = a0 + c4.y, a2 = a1 + c4.z, a3 = a2 + c4.w;
        float ta = a3;
#pragma unroll
        for (int o = 1; o < 64; o <<= 1) {
            float xa = __shfl_up(ta, o, 64);
            if (l >= o) ta += xa;
        }
        float ea = __shfl_up(ta, 1, 64); if (l == 0) ea = 0.0f;
        float4 P; P.x = ea; P.y = ea + a0; P.z = ea + a1; P.w = ea + a2;
        *(float4*)&PR[base] = P;
    }
    {
        const float4 m = *(const float4*)&costP[(3 << 16) + (r << 8) + (252 - (l << 2))];
        float w0 = m.w, w1_ = m.z, w2_ = m.y, w3 = m.x;
        float a0 = w0, a1 = a0 + w1_, a2 = a1 + w2_, a3 = a2 + w3;
        float ta = a3;
#pragma unroll
        for (int o = 1; o < 64; o <<= 1) {
            float xa = __shfl_up(ta, o, 64);
            if (l >= o) ta += xa;
        }
        float ea = __shfl_up(ta, 1, 64); if (l == 0) ea = 0.0f;
        float4 P; P.x = ea; P.y = ea + a0; P.z = ea + a1; P.w = ea + a2;
        *(float4*)&PRm[base] = P;
    }
}

// ---------------------------------------------------------------------------
// R5-EXACT sweep core (proven 61us config): volatile-asm pipelined, SDEPTH=4.
// R6 lesson: deeper pipelines spill (asm outputs CAN be spilled between issue
// and use). DEPTH=4 fits in 88 VGPR -- do not deepen in this fused kernel.
// ---------------------------------------------------------------------------
#define SDEPTH 4

template<int VD> static __device__ __forceinline__ int row_of(int ii) {
    int c = ii > 255 ? 255 : ii;
    return VD ? c : 255 - c;
}
template<int VD> static __device__ __forceinline__ int rowp_of(int ii) {
    int c = ii - 1; c = c < 0 ? 0 : (c > 255 ? 255 : c);
    return VD ? c : 255 - c;
}

template<int M, int VD>
static __device__ __forceinline__ void sweep_run(
    int l, int sr, int sc,
    const float* __restrict__ PRu,
    const float* __restrict__ cInP,
    const float* __restrict__ cStP,
    const float* __restrict__ cDeP,
    float* __restrict__ O)
{
    const int lane4 = l << 2;
    f32x4 sv = {BIGV, BIGV, BIGV, BIGV};
    {
        int kk = sc - lane4;
        if (kk == 0) sv[0] = 0.0f;
        if (kk == 1) sv[1] = 0.0f;
        if (kk == 2) sv[2] = 0.0f;
        if (kk == 3) sv[3] = 0.0f;
    }
    const int iStart = VD ? sr : 255 - sr;

    f32x4 bPR[SDEPTH], bI[SDEPTH], bS[SDEPTH], bD[SDEPTH];
    f32x4 Dp = {BIGV, BIGV, BIGV, BIGV};

#define KXc(v) (M ? (v)[3] : (v)[0])
#define KYc(v) (M ? (v)[2] : (v)[1])
#define KZc(v) (M ? (v)[1] : (v)[2])
#define KWc(v) (M ? (v)[0] : (v)[3])

#define SW_ISSUE(slot, jn) do {                                               \
        int rP_ = row_of<VD>(jn), rC_ = rowp_of<VD>(jn);                      \
        int voffP_ = ((rP_ << 8) + lane4) << 2;                               \
        int voffC_ = (M ? ((rC_ << 8) + 252 - lane4)                          \
                        : ((rC_ << 8) + lane4)) << 2;                         \
        asm volatile("global_load_dwordx4 %0, %1, %2"                         \
                     : "=v"(bPR[slot]) : "v"(voffP_), "s"(PRu));              \
        asm volatile("global_load_dwordx4 %0, %1, %2"                         \
                     : "=v"(bI[slot])  : "v"(voffC_), "s"(cInP));             \
        asm volatile("global_load_dwordx4 %0, %1, %2"                         \
                     : "=v"(bS[slot])  : "v"(voffC_), "s"(cStP));             \
        asm volatile("global_load_dwordx4 %0, %1, %2"                         \
                     : "=v"(bD[slot])  : "v"(voffC_), "s"(cDeP));             \
    } while (0)

#define SW_WAIT(n) do {                                                       \
        asm volatile("s_waitcnt vmcnt(" #n ")");                              \
        __builtin_amdgcn_sched_barrier(0);                                    \
    } while (0)

#define SW_BODY(slot, ivar) do {                                              \
        const int i__ = (ivar);                                               \
        const int r__ = VD ? i__ : 255 - i__;                                 \
        f32x4 PRc = bPR[slot];                                                \
        float tS0 = Dp[0] + KXc(bS[slot]), tS1 = Dp[1] + KYc(bS[slot]);       \
        float tS2 = Dp[2] + KZc(bS[slot]), tS3 = Dp[3] + KWc(bS[slot]);       \
        float tI0 = Dp[0] + KXc(bI[slot]), tI1 = Dp[1] + KYc(bI[slot]);       \
        float tI2 = Dp[2] + KZc(bI[slot]), tI3 = Dp[3] + KWc(bI[slot]);       \
        float tD0 = Dp[0] + KXc(bD[slot]), tD1 = Dp[1] + KYc(bD[slot]);       \
        float tD2 = Dp[2] + KZc(bD[slot]), tD3 = Dp[3] + KWc(bD[slot]);       \
        float tIm = dpp_mv<0x138, 0xF>(tI3);   /* wave_shr1 */                \
        float tDn = dpp_mv<0x130, 0xF>(tD0);   /* wave_shl1 */                \
        f32x4 cand;                                                           \
        cand[0] = fminf(tS0, fminf(tIm, tD1));                                \
        cand[1] = fminf(tS1, fminf(tI0, tD2));                                \
        cand[2] = fminf(tS2, fminf(tI1, tD3));                                \
        cand[3] = fminf(tS3, fminf(tI2, tDn));                                \
        if (i__ == iStart) {                                                  \
            cand[0] = fminf(cand[0], sv[0]); cand[1] = fminf(cand[1], sv[1]); \
            cand[2] = fminf(cand[2], sv[2]); cand[3] = fminf(cand[3], sv[3]); \
        }                                                                     \
        float z0 = cand[0] - PRc[0];                                          \
        float z1 = fminf(cand[1] - PRc[1], z0);                               \
        float z2 = fminf(cand[2] - PRc[2], z1);                               \
        float z3 = fminf(cand[3] - PRc[3], z2);                               \
        float w__ = wave_prefmin(z3);                                         \
        float e__ = dpp_mv<0x138, 0xF>(w__);   /* exclusive prefix */         \
        f32x4 D__;                                                            \
        D__[0] = PRc[0] + fminf(z0, e__);                                     \
        D__[1] = PRc[1] + fminf(z1, e__);                                     \
        D__[2] = PRc[2] + fminf(z2, e__);                                     \
        D__[3] = PRc[3] + fminf(z3, e__);                                     \
        int voffO_ = ((r__ << 8) + lane4) << 2;                               \
        asm volatile("global_store_dwordx4 %0, %1, %2"                        \
                     :: "v"(voffO_), "v"(D__), "s"(O));                       \
        Dp = D__;                                                             \
        SW_ISSUE(slot, i__ + SDEPTH);                                         \
    } while (0)

    // prologue: issue groups for rows 0..3 (16 loads in flight)
#pragma unroll
    for (int k = 0; k < SDEPTH; ++k) SW_ISSUE(k, k);

    // peeled rows 0..3 (exact FIFO counts), then steady state vmcnt(15)
    SW_WAIT(12); SW_BODY(0, 0);
    SW_WAIT(13); SW_BODY(1, 1);
    SW_WAIT(14); SW_BODY(2, 2);
    SW_WAIT(15); SW_BODY(3, 3);
    for (int ib = SDEPTH; ib < 256; ib += SDEPTH) {
        SW_WAIT(15); SW_BODY(0, ib + 0);
        SW_WAIT(15); SW_BODY(1, ib + 1);
        SW_WAIT(15); SW_BODY(2, ib + 2);
        SW_WAIT(15); SW_BODY(3, ib + 3);
    }
    asm volatile("s_waitcnt vmcnt(0)");   // drain stores before endpgm

#undef SW_ISSUE
#undef SW_WAIT
#undef SW_BODY
#undef KXc
#undef KYc
#undef KZc
#undef KWc
}

// ---------------------------------------------------------------------------
// Kernel 3 (R19): blocks 0..3 = R5-exact sweeps. Blocks 4..515 = heuristic
// HALF-blocks: 512 independent 256-thread blocks (R7 lesson: 512-thread
// fusion spills; keep the proven 256-thread/88-VGPR codegen shape). Block
// 4+h (h=tile + 256*half) processes channels [half*64, half*64+64) of tile,
// writing partial gm/va/hv (34 floats/px) to workspace. 512 blocks -> 2
// blocks/CU = 2 waves/SIMD with per-wave serial work halved. k_merge sums
// partials and runs the MLP epilogue (+ vend).
// ---------------------------------------------------------------------------
__global__ __launch_bounds__(256) void k_main(
    const float* __restrict__ feat,
    const float* __restrict__ w1,
    const int* __restrict__ endn,
    const float* __restrict__ costP, const float* __restrict__ PR,
    const float* __restrict__ PRm, const int* __restrict__ startn,
    float* __restrict__ distQ, float* __restrict__ part)
{
    if (blockIdx.x < 4) {
        const int l = threadIdx.x;
        if (l >= 64) return;
        __builtin_amdgcn_s_setprio(1);     // latency-critical chain wins issue
        const int sw  = blockIdx.x;
        const int sr  = startn[0];
        const int sc0 = startn[1];
        float* O = distQ + (sw << 16);
        if (sw == 0)
            sweep_run<0,1>(l, sr, sc0,       PR,  costP + (7<<16), costP + (6<<16), costP + (5<<16), O);
        else if (sw == 1)
            sweep_run<1,1>(l, sr, 255 - sc0, PRm, costP + (5<<16), costP + (6<<16), costP + (7<<16), O);
        else if (sw == 2)
            sweep_run<0,0>(l, sr, sc0,       PR,  costP + (2<<16), costP + (1<<16), costP + (0<<16), O);
        else
            sweep_run<1,0>(l, sr, 255 - sc0, PRm, costP + (0<<16), costP + (1<<16), costP + (2<<16), O);
        return;
    }

    // ============== HEURISTIC HALF-BLOCK (channels half*64 .. +63) =========
    __shared__ float  stage[CHUNK * SP];    // 41.6 KB
    __shared__ float4 w1L[64 * 8];          // 8 KB (this half's rows)
    __shared__ float  endfL[64];

    const int t    = threadIdx.x;
    const int hb   = blockIdx.x - 4;
    const int tile = hb & 255;
    const int half = hb >> 8;               // 0: ch 0..63 (+abs), 1: 64..127 (+var)
    const int r0   = (tile >> 4) * TILE;
    const int c0   = (tile & 15) * TILE;
    const int chB  = half << 6;

    for (int i = t; i < 64 * 8; i += 256) w1L[i] = ((const float4*)w1)[(half << 9) + i];
    const int er = endn[0], ec = endn[1];
    if (half == 0 && t < 64) endfL[t] = feat[(er * Wd + ec) * Cd + t];

    const int lr = t >> 4, lc = t & 15;
    const int r = r0 + lr, c = c0 + lc;
    const int px0 = (lr + 1) * HPX + (lc + 1);

    float4 hv[8];
#pragma unroll
    for (int j = 0; j < 8; ++j) hv[j] = make_float4(0.f, 0.f, 0.f, 0.f);
    float gm_acc = 0.0f, va_acc = 0.0f;     // va = abs^2 (half0) / var (half1)

    for (int cc = 0; cc < 2; ++cc) {
        const int ch0 = chB + (cc << 5);    // this half's 32-ch chunk base
        __syncthreads();
        for (int i = t; i < PXN * 8; i += 256) {
            int pxi = i >> 3, f4 = i & 7;
            int pr = pxi / HPX;
            int pc = pxi - pr * HPX;
            int gr = r0 - 1 + pr, gc = c0 - 1 + pc;
            float4 v = make_float4(0.f, 0.f, 0.f, 0.f);
            if ((unsigned)gr < Hd && (unsigned)gc < Wd) {
                v = *reinterpret_cast<const float4*>(
                        &feat[(((gr << 8) + gc) * Cd) + ch0 + (f4 << 2)]);
            }
            int chb = f4 << 2;
            stage[(chb + 0) * SP + pxi] = v.x;
            stage[(chb + 1) * SP + pxi] = v.y;
            stage[(chb + 2) * SP + pxi] = v.z;
            stage[(chb + 3) * SP + pxi] = v.w;
        }
        __syncthreads();
        for (int ch = 0; ch < CHUNK; ++ch) {
            const float* pl = stage + ch * SP + px0;
            float x  = pl[0];
            float n0 = pl[-HPX - 1], n1 = pl[-HPX], n2 = pl[-HPX + 1];
            float n3 = pl[-1],                      n4 = pl[1];
            float n5 = pl[HPX - 1],  n6 = pl[HPX],  n7 = pl[HPX + 1];

            float gx = (n2 + 2.f * n4 + n7) - (n0 + 2.f * n3 + n5);
            float gy = (n5 + 2.f * n6 + n7) - (n0 + 2.f * n1 + n2);
            gm_acc += sqrtf(gx * gx + gy * gy);

            if (half) {   // ch>=64: local variance
                float s1 = x + n0 + n1 + n2 + n3 + n4 + n5 + n6 + n7;
                float s2 = x*x + n0*n0 + n1*n1 + n2*n2 + n3*n3 + n4*n4
                         + n5*n5 + n6*n6 + n7*n7;
                float m = s1 * (1.0f / 9.0f);
                va_acc += s2 * (1.0f / 9.0f) - m * m;
            } else {      // ch<64: absorption distance^2
                float dlf = x - endfL[(cc << 5) + ch];
                va_acc = fmaf(dlf, dlf, va_acc);
            }

            const float4* __restrict__ wr4 = &w1L[((cc << 5) + ch) << 3];
#pragma unroll
            for (int j4 = 0; j4 < 8; ++j4) {
                float4 wv = wr4[j4];
                hv[j4].x = fmaf(x, wv.x, hv[j4].x);
                hv[j4].y = fmaf(x, wv.y, hv[j4].y);
                hv[j4].z = fmaf(x, wv.z, hv[j4].z);
                hv[j4].w = fmaf(x, wv.w, hv[j4].w);
            }
        }
    }

    // write partials: planes [half*34 .. half*34+33]: gm, va, hv[0..31]
    const int p = (r << 8) + c;
    float* __restrict__ pb = part + (half * 34) * 65536;
    pb[p]           = gm_acc;
    pb[65536 + p]   = va_acc;
#pragma unroll
    for (int j4 = 0; j4 < 8; ++j4) {
        pb[(2 + (j4 << 2) + 0) * 65536 + p] = hv[j4].x;
        pb[(2 + (j4 << 2) + 1) * 65536 + p] = hv[j4].y;
        pb[(2 + (j4 << 2) + 2) * 65536 + p] = hv[j4].z;
        pb[(2 + (j4 << 2) + 3) * 65536 + p] = hv[j4].w;
    }
}

// ---------------------------------------------------------------------------
// Kernel 4 (R19): merge quadrant dist planes AND finish the heuristic
// (sum partials, MLP epilogue, end-node variance).
// ---------------------------------------------------------------------------
__global__ __launch_bounds__(256) void k_merge(
    const float* __restrict__ feat,
    const float* __restrict__ b1, const float* __restrict__ w2,
    const float* __restrict__ b2, const float* __restrict__ dlt,
    const float* __restrict__ gmm, const float* __restrict__ bta,
    const int* __restrict__ endn,
    const float* __restrict__ distQ, const float* __restrict__ part,
    float* __restrict__ out)
{
    __shared__ float vendL[64];
    __shared__ float vendS_;

    const int t = threadIdx.x;
    const int p = blockIdx.x * 256 + t;

    const int er = endn[0], ec = endn[1];
    if (t < 64) {
        float s1 = 0.0f, s2 = 0.0f;
#pragma unroll
        for (int dr = -1; dr <= 1; ++dr)
#pragma unroll
            for (int dc = -1; dc <= 1; ++dc) {
                int gr = er + dr, gc = ec + dc;
                if ((unsigned)gr < Hd && (unsigned)gc < Wd) {
                    float x = feat[((gr << 8) + gc) * Cd + 64 + t];
                    s1 += x; s2 = fmaf(x, x, s2);
                }
            }
        float m = s1 * (1.0f / 9.0f);
        vendL[t] = s2 * (1.0f / 9.0f) - m * m;
    }
    __syncthreads();
    if (t < 64) {
        float v = vendL[t];
#pragma unroll
        for (int o = 32; o > 0; o >>= 1) v += __shfl_down(v, o, 64);
        if (t == 0) vendS_ = v;
    }
    __syncthreads();
    const float vend = vendS_;

    // ---- heuristic epilogue from partials ----
    const float* __restrict__ p0 = part;                  // half0: gm, abs2, hv
    const float* __restrict__ p1 = part + 34 * 65536;     // half1: gm, var, hv
    float gm   = p0[p] + p1[p];
    float abs2 = p0[65536 + p];
    float var  = p1[65536 + p];
    float o = b2[0];
#pragma unroll
    for (int j = 0; j < 32; ++j) {
        float hj = p0[(2 + j) * 65536 + p] + p1[(2 + j) * 65536 + p] + b1[j];
        o = fmaf(fmaxf(hj, 0.0f), w2[j], o);
    }
    float omg = 1.0f / (1.0f + expf(-o));
    float dS = softplus_f(dlt[0]);
    float gS = softplus_f(gmm[0]);
    float bS = softplus_f(bta[0]);
    float heur = dS * (gm * (1.0f / 128.0f)) + omg * gS * (vend - var)
               + (1.0f - omg) * bS * sqrtf(abs2);
    out[p * 10] = fmaxf(heur, 0.0f);

    // ---- dist merge (un-mirroring planes 1,3) ----
    int pm = (p & ~255) + (255 - (p & 255));
    float v = fminf(fminf(distQ[p],              distQ[(2 << 16) + p]),
                    fminf(distQ[(1 << 16) + pm], distQ[(3 << 16) + pm]));
    out[p * 10 + 9] = fminf(v, BIGV);
}

// ---------------------------------------------------------------------------
extern "C" void kernel_launch(void* const* d_in, const int* in_sizes, int n_in,
                              void* d_out, int out_size, void* d_ws, size_t ws_size,
                              hipStream_t stream)
{
    const float* feat  = (const float*)d_in[0];
    const float* dlt   = (const float*)d_in[1];
    const float* gmm   = (const float*)d_in[2];
    const float* bta   = (const float*)d_in[3];
    const float* w1    = (const float*)d_in[4];
    const float* b1    = (const float*)d_in[5];
    const float* w2    = (const float*)d_in[6];
    const float* b2    = (const float*)d_in[7];
    const int*   startn= (const int*)d_in[8];
    const int*   endn  = (const int*)d_in[9];
    float* out = (float*)d_out;
    float* ws  = (float*)d_ws;

    float* costP = ws;                   // 8 planes
    float* PR    = ws + 8  * 65536;
    float* PRm   = ws + 9  * 65536;
    float* distQ = ws + 10 * 65536;      // 4 quadrant planes
    float* part  = ws + 14 * 65536;      // 68 partial planes (17.8 MB)

    dim3 g16(16, 16);
    k_cost<<<g16, 256, 0, stream>>>(feat, out, costP);
    k_scan<<<256, 64, 0, stream>>>(costP, PR, PRm);
    k_main<<<516, 256, 0, stream>>>(feat, w1, endn,
                                    costP, PR, PRm, startn, distQ, part);
    k_merge<<<256, 256, 0, stream>>>(feat, b1, w2, b2, dlt, gmm, bta, endn,
                                     distQ, part, out);
}

// Round 9
// 163.215 us; speedup vs baseline: 4.2375x; 1.0316x over previous
//
#include <hip/hip_runtime.h>
#include <math.h>

#define Hd 256
#define Wd 256
#define Cd 128
#define BIGV 1.0e9f

typedef float f32x4 __attribute__((ext_vector_type(4)));

static __device__ __forceinline__ float softplus_f(float x) {
    return fmaxf(x, 0.0f) + log1pf(expf(-fabsf(x)));
}

// ---- DPP helpers (gfx9/CDNA DPP controls; old = FLT_MAX = min identity) ----
#define FMAXBITS 0x7F7FFFFF
template<int CTRL, int RM>
static __device__ __forceinline__ float dpp_mv(float x) {
    return __int_as_float(__builtin_amdgcn_update_dpp(
        FMAXBITS, __float_as_int(x), CTRL, RM, 0xF, false));
}
template<int CTRL, int RM>
static __device__ __forceinline__ float dpp_min(float x) {
    return fminf(x, dpp_mv<CTRL, RM>(x));
}
// inclusive prefix-min across 64 lanes
static __device__ __forceinline__ float wave_prefmin(float x) {
    x = dpp_min<0x111, 0xF>(x);   // row_shr:1
    x = dpp_min<0x112, 0xF>(x);   // row_shr:2
    x = dpp_min<0x114, 0xF>(x);   // row_shr:4
    x = dpp_min<0x118, 0xF>(x);   // row_shr:8
    x = dpp_min<0x142, 0xA>(x);   // row_bcast15 -> rows 1,3
    x = dpp_min<0x143, 0xC>(x);   // row_bcast31 -> rows 2,3
    return x;
}

#define TILE 16
#define HPX 18
#define PXN 324
#define SP  325
#define CHUNK 32

// ---------------------------------------------------------------------------
// Kernel 1 (R20): COST PARTIALS. 512 blocks (tile, half); each computes the
// partial 8-dir dot products + partial norm over its 64 channels (2 staged
// 32-ch chunks). 2 blocks/CU (was 1) -> staging/LDS latency overlapped.
// The old norm-over-halo pass is deleted: neighbor norms now come from the
// complete global partial planes in k_scan's finisher.
// ---------------------------------------------------------------------------
__global__ __launch_bounds__(256) void k_costp(
    const float* __restrict__ feat, float* __restrict__ pcost)
{
    __shared__ float stage[CHUNK * SP];     // 41.6 KB

    const int t    = threadIdx.x;
    const int hb   = blockIdx.x;
    const int tile = hb & 255;
    const int half = hb >> 8;               // channels [half*64, half*64+64)
    const int r0   = (tile >> 4) * TILE;
    const int c0   = (tile & 15) * TILE;

    const int lr = t >> 4, lc = t & 15;
    const int r = r0 + lr, c = c0 + lc;
    const int px0 = (lr + 1) * HPX + (lc + 1);

    float dotv[8];
#pragma unroll
    for (int j = 0; j < 8; ++j) dotv[j] = 0.0f;
    float nrm_acc = 0.0f;

    for (int cc = 0; cc < 2; ++cc) {
        const int ch0 = (half << 6) + (cc << 5);
        __syncthreads();
        for (int i = t; i < PXN * 8; i += 256) {
            int pxi = i >> 3, f4 = i & 7;
            int pr = pxi / HPX;
            int pc = pxi - pr * HPX;
            int gr = r0 - 1 + pr, gc = c0 - 1 + pc;
            float4 v = make_float4(0.f, 0.f, 0.f, 0.f);
            if ((unsigned)gr < Hd && (unsigned)gc < Wd) {
                v = *reinterpret_cast<const float4*>(
                        &feat[(((gr << 8) + gc) * Cd) + ch0 + (f4 << 2)]);
            }
            int chb = f4 << 2;
            stage[(chb + 0) * SP + pxi] = v.x;
            stage[(chb + 1) * SP + pxi] = v.y;
            stage[(chb + 2) * SP + pxi] = v.z;
            stage[(chb + 3) * SP + pxi] = v.w;
        }
        __syncthreads();
        for (int ch = 0; ch < CHUNK; ++ch) {
            const float* pl = stage + ch * SP + px0;
            float x  = pl[0];
            float n0 = pl[-HPX - 1], n1 = pl[-HPX], n2 = pl[-HPX + 1];
            float n3 = pl[-1],                      n4 = pl[1];
            float n5 = pl[HPX - 1],  n6 = pl[HPX],  n7 = pl[HPX + 1];

            nrm_acc = fmaf(x, x, nrm_acc);
            dotv[0] = fmaf(x, n0, dotv[0]);
            dotv[1] = fmaf(x, n1, dotv[1]);
            dotv[2] = fmaf(x, n2, dotv[2]);
            dotv[3] = fmaf(x, n3, dotv[3]);
            dotv[4] = fmaf(x, n4, dotv[4]);
            dotv[5] = fmaf(x, n5, dotv[5]);
            dotv[6] = fmaf(x, n6, dotv[6]);
            dotv[7] = fmaf(x, n7, dotv[7]);
        }
    }

    const int p = (r << 8) + c;
    float* __restrict__ pb = pcost + (half * 9) * 65536;
    pb[p] = nrm_acc;
#pragma unroll
    for (int j = 0; j < 8; ++j) pb[((1 + j) << 16) + p] = dotv[j];
}

// ---------------------------------------------------------------------------
// Kernel 2 (R20): cost FINISH + per-row prefix scans, fused. One block per
// row, 256 threads. Phase A: stage summed norms of rows r-1..r+1 in LDS,
// each thread finishes its pixel's 8 costs (dot0+dot1, np*nn) -> costP + out
// channels 1..8, parking the E/W rows in LDS. Phase B: lanes <64 run the
// proven exclusive prefix scans from LDS (identical math to the old k_scan).
// ---------------------------------------------------------------------------
__global__ __launch_bounds__(256) void k_scan(
    const float* __restrict__ pcost, float* __restrict__ costP,
    float* __restrict__ PR, float* __restrict__ PRm,
    float* __restrict__ out)
{
    __shared__ float nrm[3 * 256];
    __shared__ float cE[256], cW[256];

    const int t = threadIdx.x;
    const int r = blockIdx.x;

    const float* __restrict__ ph0 = pcost;
    const float* __restrict__ ph1 = pcost + 9 * 65536;

    for (int i = t; i < 3 * 256; i += 256) {
        int rr = r - 1 + (i >> 8);
        int pc = i & 255;
        float s = 0.0f;
        if ((unsigned)rr < Hd) s = ph0[(rr << 8) + pc] + ph1[(rr << 8) + pc];
        nrm[i] = fmaxf(sqrtf(s), 1e-12f);
    }
    __syncthreads();

    const int p = (r << 8) + t;
    const float npv = nrm[256 + t];
    const int drr[8] = {-1,-1,-1, 0, 0, 1, 1, 1};
    const int dcc[8] = {-1, 0, 1,-1, 1,-1, 0, 1};
#pragma unroll
    for (int j = 0; j < 8; ++j) {
        int nr = r + drr[j], nc = t + dcc[j];
        float cj;
        if ((unsigned)nr < Hd && (unsigned)nc < Wd) {
            float dot = ph0[((1 + j) << 16) + p] + ph1[((1 + j) << 16) + p];
            float nn  = nrm[((drr[j] + 1) << 8) + nc];
            cj = 1.0f - dot / (npv * nn);
        } else {
            cj = BIGV;
        }
        costP[(j << 16) + p] = cj;
        out[p * 10 + 1 + j]  = cj;
        if (j == 4) cE[t] = cj;
        if (j == 3) cW[t] = cj;
    }
    __syncthreads();

    if (t < 64) {
        const int l = t;
        const int base = (r << 8) + (l << 2);
        {   // east scan (plane 4)
            float a0 = cE[(l << 2) + 0];
            float a1 = a0 + cE[(l << 2) + 1];
            float a2 = a1 + cE[(l << 2) + 2];
            float a3 = a2 + cE[(l << 2) + 3];
            float ta = a3;
#pragma unroll
            for (int o = 1; o < 64; o <<= 1) {
                float xa = __shfl_up(ta, o, 64);
                if (l >= o) ta += xa;
            }
            float ea = __shfl_up(ta, 1, 64); if (l == 0) ea = 0.0f;
            float4 P; P.x = ea; P.y = ea + a0; P.z = ea + a1; P.w = ea + a2;
            *(float4*)&PR[base] = P;
        }
        {   // west scan, mirrored (plane 3)
            float w0 = cW[255 - (l << 2)];
            float w1_ = cW[254 - (l << 2)];
            float w2_ = cW[253 - (l << 2)];
            float w3 = cW[252 - (l << 2)];
            float a0 = w0, a1 = a0 + w1_, a2 = a1 + w2_, a3 = a2 + w3;
            float ta = a3;
#pragma unroll
            for (int o = 1; o < 64; o <<= 1) {
                float xa = __shfl_up(ta, o, 64);
                if (l >= o) ta += xa;
            }
            float ea = __shfl_up(ta, 1, 64); if (l == 0) ea = 0.0f;
            float4 P; P.x = ea; P.y = ea + a0; P.z = ea + a1; P.w = ea + a2;
            *(float4*)&PRm[base] = P;
        }
    }
}

// ---------------------------------------------------------------------------
// R5-EXACT sweep core (proven): volatile-asm pipelined, SDEPTH=4.
// R6 lesson: deeper pipelines spill. DEPTH=4 fits (slot-reuse alloc, no
// scratch -- R8 WRITE_SIZE == partials+distQ exactly). Do not deepen.
// ---------------------------------------------------------------------------
#define SDEPTH 4

template<int VD> static __device__ __forceinline__ int row_of(int ii) {
    int c = ii > 255 ? 255 : ii;
    return VD ? c : 255 - c;
}
template<int VD> static __device__ __forceinline__ int rowp_of(int ii) {
    int c = ii - 1; c = c < 0 ? 0 : (c > 255 ? 255 : c);
    return VD ? c : 255 - c;
}

template<int M, int VD>
static __device__ __forceinline__ void sweep_run(
    int l, int sr, int sc,
    const float* __restrict__ PRu,
    const float* __restrict__ cInP,
    const float* __restrict__ cStP,
    const float* __restrict__ cDeP,
    float* __restrict__ O)
{
    const int lane4 = l << 2;
    f32x4 sv = {BIGV, BIGV, BIGV, BIGV};
    {
        int kk = sc - lane4;
        if (kk == 0) sv[0] = 0.0f;
        if (kk == 1) sv[1] = 0.0f;
        if (kk == 2) sv[2] = 0.0f;
        if (kk == 3) sv[3] = 0.0f;
    }
    const int iStart = VD ? sr : 255 - sr;

    f32x4 bPR[SDEPTH], bI[SDEPTH], bS[SDEPTH], bD[SDEPTH];
    f32x4 Dp = {BIGV, BIGV, BIGV, BIGV};

#define KXc(v) (M ? (v)[3] : (v)[0])
#define KYc(v) (M ? (v)[2] : (v)[1])
#define KZc(v) (M ? (v)[1] : (v)[2])
#define KWc(v) (M ? (v)[0] : (v)[3])

#define SW_ISSUE(slot, jn) do {                                               \
        int rP_ = row_of<VD>(jn), rC_ = rowp_of<VD>(jn);                      \
        int voffP_ = ((rP_ << 8) + lane4) << 2;                               \
        int voffC_ = (M ? ((rC_ << 8) + 252 - lane4)                          \
                        : ((rC_ << 8) + lane4)) << 2;                         \
        asm volatile("global_load_dwordx4 %0, %1, %2"                         \
                     : "=v"(bPR[slot]) : "v"(voffP_), "s"(PRu));              \
        asm volatile("global_load_dwordx4 %0, %1, %2"                         \
                     : "=v"(bI[slot])  : "v"(voffC_), "s"(cInP));             \
        asm volatile("global_load_dwordx4 %0, %1, %2"                         \
                     : "=v"(bS[slot])  : "v"(voffC_), "s"(cStP));             \
        asm volatile("global_load_dwordx4 %0, %1, %2"                         \
                     : "=v"(bD[slot])  : "v"(voffC_), "s"(cDeP));             \
    } while (0)

#define SW_WAIT(n) do {                                                       \
        asm volatile("s_waitcnt vmcnt(" #n ")");                              \
        __builtin_amdgcn_sched_barrier(0);                                    \
    } while (0)

#define SW_BODY(slot, ivar) do {                                              \
        const int i__ = (ivar);                                               \
        const int r__ = VD ? i__ : 255 - i__;                                 \
        f32x4 PRc = bPR[slot];                                                \
        float tS0 = Dp[0] + KXc(bS[slot]), tS1 = Dp[1] + KYc(bS[slot]);       \
        float tS2 = Dp[2] + KZc(bS[slot]), tS3 = Dp[3] + KWc(bS[slot]);       \
        float tI0 = Dp[0] + KXc(bI[slot]), tI1 = Dp[1] + KYc(bI[slot]);       \
        float tI2 = Dp[2] + KZc(bI[slot]), tI3 = Dp[3] + KWc(bI[slot]);       \
        float tD0 = Dp[0] + KXc(bD[slot]), tD1 = Dp[1] + KYc(bD[slot]);       \
        float tD2 = Dp[2] + KZc(bD[slot]), tD3 = Dp[3] + KWc(bD[slot]);       \
        float tIm = dpp_mv<0x138, 0xF>(tI3);   /* wave_shr1 */                \
        float tDn = dpp_mv<0x130, 0xF>(tD0);   /* wave_shl1 */                \
        f32x4 cand;                                                           \
        cand[0] = fminf(tS0, fminf(tIm, tD1));                                \
        cand[1] = fminf(tS1, fminf(tI0, tD2));                                \
        cand[2] = fminf(tS2, fminf(tI1, tD3));                                \
        cand[3] = fminf(tS3, fminf(tI2, tDn));                                \
        if (i__ == iStart) {                                                  \
            cand[0] = fminf(cand[0], sv[0]); cand[1] = fminf(cand[1], sv[1]); \
            cand[2] = fminf(cand[2], sv[2]); cand[3] = fminf(cand[3], sv[3]); \
        }                                                                     \
        float z0 = cand[0] - PRc[0];                                          \
        float z1 = fminf(cand[1] - PRc[1], z0);                               \
        float z2 = fminf(cand[2] - PRc[2], z1);                               \
        float z3 = fminf(cand[3] - PRc[3], z2);                               \
        float w__ = wave_prefmin(z3);                                         \
        float e__ = dpp_mv<0x138, 0xF>(w__);   /* exclusive prefix */         \
        f32x4 D__;                                                            \
        D__[0] = PRc[0] + fminf(z0, e__);                                     \
        D__[1] = PRc[1] + fminf(z1, e__);                                     \
        D__[2] = PRc[2] + fminf(z2, e__);                                     \
        D__[3] = PRc[3] + fminf(z3, e__);                                     \
        int voffO_ = ((r__ << 8) + lane4) << 2;                               \
        asm volatile("global_store_dwordx4 %0, %1, %2"                        \
                     :: "v"(voffO_), "v"(D__), "s"(O));                       \
        Dp = D__;                                                             \
        SW_ISSUE(slot, i__ + SDEPTH);                                         \
    } while (0)

#pragma unroll
    for (int k = 0; k < SDEPTH; ++k) SW_ISSUE(k, k);

    SW_WAIT(12); SW_BODY(0, 0);
    SW_WAIT(13); SW_BODY(1, 1);
    SW_WAIT(14); SW_BODY(2, 2);
    SW_WAIT(15); SW_BODY(3, 3);
    for (int ib = SDEPTH; ib < 256; ib += SDEPTH) {
        SW_WAIT(15); SW_BODY(0, ib + 0);
        SW_WAIT(15); SW_BODY(1, ib + 1);
        SW_WAIT(15); SW_BODY(2, ib + 2);
        SW_WAIT(15); SW_BODY(3, ib + 3);
    }
    asm volatile("s_waitcnt vmcnt(0)");   // drain stores before endpgm

#undef SW_ISSUE
#undef SW_WAIT
#undef SW_BODY
#undef KXc
#undef KYc
#undef KZc
#undef KWc
}

// ---------------------------------------------------------------------------
// Kernel 3 (R8-proven, unchanged): blocks 0..3 = sweeps; 4..515 = heuristic
// half-blocks writing partials. R7 lesson: never >256 threads/block here.
// ---------------------------------------------------------------------------
__global__ __launch_bounds__(256) void k_main(
    const float* __restrict__ feat,
    const float* __restrict__ w1,
    const int* __restrict__ endn,
    const float* __restrict__ costP, const float* __restrict__ PR,
    const float* __restrict__ PRm, const int* __restrict__ startn,
    float* __restrict__ distQ, float* __restrict__ part)
{
    if (blockIdx.x < 4) {
        const int l = threadIdx.x;
        if (l >= 64) return;
        __builtin_amdgcn_s_setprio(1);
        const int sw  = blockIdx.x;
        const int sr  = startn[0];
        const int sc0 = startn[1];
        float* O = distQ + (sw << 16);
        if (sw == 0)
            sweep_run<0,1>(l, sr, sc0,       PR,  costP + (7<<16), costP + (6<<16), costP + (5<<16), O);
        else if (sw == 1)
            sweep_run<1,1>(l, sr, 255 - sc0, PRm, costP + (5<<16), costP + (6<<16), costP + (7<<16), O);
        else if (sw == 2)
            sweep_run<0,0>(l, sr, sc0,       PR,  costP + (2<<16), costP + (1<<16), costP + (0<<16), O);
        else
            sweep_run<1,0>(l, sr, 255 - sc0, PRm, costP + (0<<16), costP + (1<<16), costP + (2<<16), O);
        return;
    }

    // ============== HEURISTIC HALF-BLOCK (channels half*64 .. +63) =========
    __shared__ float  stage[CHUNK * SP];
    __shared__ float4 w1L[64 * 8];
    __shared__ float  endfL[64];

    const int t    = threadIdx.x;
    const int hb   = blockIdx.x - 4;
    const int tile = hb & 255;
    const int half = hb >> 8;
    const int r0   = (tile >> 4) * TILE;
    const int c0   = (tile & 15) * TILE;
    const int chB  = half << 6;

    for (int i = t; i < 64 * 8; i += 256) w1L[i] = ((const float4*)w1)[(half << 9) + i];
    const int er = endn[0], ec = endn[1];
    if (half == 0 && t < 64) endfL[t] = feat[(er * Wd + ec) * Cd + t];

    const int lr = t >> 4, lc = t & 15;
    const int r = r0 + lr, c = c0 + lc;
    const int px0 = (lr + 1) * HPX + (lc + 1);

    float4 hv[8];
#pragma unroll
    for (int j = 0; j < 8; ++j) hv[j] = make_float4(0.f, 0.f, 0.f, 0.f);
    float gm_acc = 0.0f, va_acc = 0.0f;

    for (int cc = 0; cc < 2; ++cc) {
        const int ch0 = chB + (cc << 5);
        __syncthreads();
        for (int i = t; i < PXN * 8; i += 256) {
            int pxi = i >> 3, f4 = i & 7;
            int pr = pxi / HPX;
            int pc = pxi - pr * HPX;
            int gr = r0 - 1 + pr, gc = c0 - 1 + pc;
            float4 v = make_float4(0.f, 0.f, 0.f, 0.f);
            if ((unsigned)gr < Hd && (unsigned)gc < Wd) {
                v = *reinterpret_cast<const float4*>(
                        &feat[(((gr << 8) + gc) * Cd) + ch0 + (f4 << 2)]);
            }
            int chb = f4 << 2;
            stage[(chb + 0) * SP + pxi] = v.x;
            stage[(chb + 1) * SP + pxi] = v.y;
            stage[(chb + 2) * SP + pxi] = v.z;
            stage[(chb + 3) * SP + pxi] = v.w;
        }
        __syncthreads();
        for (int ch = 0; ch < CHUNK; ++ch) {
            const float* pl = stage + ch * SP + px0;
            float x  = pl[0];
            float n0 = pl[-HPX - 1], n1 = pl[-HPX], n2 = pl[-HPX + 1];
            float n3 = pl[-1],                      n4 = pl[1];
            float n5 = pl[HPX - 1],  n6 = pl[HPX],  n7 = pl[HPX + 1];

            float gx = (n2 + 2.f * n4 + n7) - (n0 + 2.f * n3 + n5);
            float gy = (n5 + 2.f * n6 + n7) - (n0 + 2.f * n1 + n2);
            gm_acc += sqrtf(gx * gx + gy * gy);

            if (half) {
                float s1 = x + n0 + n1 + n2 + n3 + n4 + n5 + n6 + n7;
                float s2 = x*x + n0*n0 + n1*n1 + n2*n2 + n3*n3 + n4*n4
                         + n5*n5 + n6*n6 + n7*n7;
                float m = s1 * (1.0f / 9.0f);
                va_acc += s2 * (1.0f / 9.0f) - m * m;
            } else {
                float dlf = x - endfL[(cc << 5) + ch];
                va_acc = fmaf(dlf, dlf, va_acc);
            }

            const float4* __restrict__ wr4 = &w1L[((cc << 5) + ch) << 3];
#pragma unroll
            for (int j4 = 0; j4 < 8; ++j4) {
                float4 wv = wr4[j4];
                hv[j4].x = fmaf(x, wv.x, hv[j4].x);
                hv[j4].y = fmaf(x, wv.y, hv[j4].y);
                hv[j4].z = fmaf(x, wv.z, hv[j4].z);
                hv[j4].w = fmaf(x, wv.w, hv[j4].w);
            }
        }
    }

    const int p = (r << 8) + c;
    float* __restrict__ pb = part + (half * 34) * 65536;
    pb[p]           = gm_acc;
    pb[65536 + p]   = va_acc;
#pragma unroll
    for (int j4 = 0; j4 < 8; ++j4) {
        pb[(2 + (j4 << 2) + 0) * 65536 + p] = hv[j4].x;
        pb[(2 + (j4 << 2) + 1) * 65536 + p] = hv[j4].y;
        pb[(2 + (j4 << 2) + 2) * 65536 + p] = hv[j4].z;
        pb[(2 + (j4 << 2) + 3) * 65536 + p] = hv[j4].w;
    }
}

// ---------------------------------------------------------------------------
// Kernel 4 (R8-proven, unchanged): merge dist planes + heuristic epilogue.
// ---------------------------------------------------------------------------
__global__ __launch_bounds__(256) void k_merge(
    const float* __restrict__ feat,
    const float* __restrict__ b1, const float* __restrict__ w2,
    const float* __restrict__ b2, const float* __restrict__ dlt,
    const float* __restrict__ gmm, const float* __restrict__ bta,
    const int* __restrict__ endn,
    const float* __restrict__ distQ, const float* __restrict__ part,
    float* __restrict__ out)
{
    __shared__ float vendL[64];
    __shared__ float vendS_;

    const int t = threadIdx.x;
    const int p = blockIdx.x * 256 + t;

    const int er = endn[0], ec = endn[1];
    if (t < 64) {
        float s1 = 0.0f, s2 = 0.0f;
#pragma unroll
        for (int dr = -1; dr <= 1; ++dr)
#pragma unroll
            for (int dc = -1; dc <= 1; ++dc) {
                int gr = er + dr, gc = ec + dc;
                if ((unsigned)gr < Hd && (unsigned)gc < Wd) {
                    float x = feat[((gr << 8) + gc) * Cd + 64 + t];
                    s1 += x; s2 = fmaf(x, x, s2);
                }
            }
        float m = s1 * (1.0f / 9.0f);
        vendL[t] = s2 * (1.0f / 9.0f) - m * m;
    }
    __syncthreads();
    if (t < 64) {
        float v = vendL[t];
#pragma unroll
        for (int o = 32; o > 0; o >>= 1) v += __shfl_down(v, o, 64);
        if (t == 0) vendS_ = v;
    }
    __syncthreads();
    const float vend = vendS_;

    const float* __restrict__ p0 = part;
    const float* __restrict__ p1 = part + 34 * 65536;
    float gm   = p0[p] + p1[p];
    float abs2 = p0[65536 + p];
    float var  = p1[65536 + p];
    float o = b2[0];
#pragma unroll
    for (int j = 0; j < 32; ++j) {
        float hj = p0[(2 + j) * 65536 + p] + p1[(2 + j) * 65536 + p] + b1[j];
        o = fmaf(fmaxf(hj, 0.0f), w2[j], o);
    }
    float omg = 1.0f / (1.0f + expf(-o));
    float dS = softplus_f(dlt[0]);
    float gS = softplus_f(gmm[0]);
    float bS = softplus_f(bta[0]);
    float heur = dS * (gm * (1.0f / 128.0f)) + omg * gS * (vend - var)
               + (1.0f - omg) * bS * sqrtf(abs2);
    out[p * 10] = fmaxf(heur, 0.0f);

    int pm = (p & ~255) + (255 - (p & 255));
    float v = fminf(fminf(distQ[p],              distQ[(2 << 16) + p]),
                    fminf(distQ[(1 << 16) + pm], distQ[(3 << 16) + pm]));
    out[p * 10 + 9] = fminf(v, BIGV);
}

// ---------------------------------------------------------------------------
extern "C" void kernel_launch(void* const* d_in, const int* in_sizes, int n_in,
                              void* d_out, int out_size, void* d_ws, size_t ws_size,
                              hipStream_t stream)
{
    const float* feat  = (const float*)d_in[0];
    const float* dlt   = (const float*)d_in[1];
    const float* gmm   = (const float*)d_in[2];
    const float* bta   = (const float*)d_in[3];
    const float* w1    = (const float*)d_in[4];
    const float* b1    = (const float*)d_in[5];
    const float* w2    = (const float*)d_in[6];
    const float* b2    = (const float*)d_in[7];
    const int*   startn= (const int*)d_in[8];
    const int*   endn  = (const int*)d_in[9];
    float* out = (float*)d_out;
    float* ws  = (float*)d_ws;

    float* costP = ws;                   // 8 planes
    float* PR    = ws + 8  * 65536;
    float* PRm   = ws + 9  * 65536;
    float* distQ = ws + 10 * 65536;      // 4 quadrant planes
    float* part  = ws + 14 * 65536;      // 68 heuristic-partial planes
    float* pcost = part;                 // 18 cost-partial planes (ALIASED:
                                         // dead before k_main writes part)

    k_costp<<<512, 256, 0, stream>>>(feat, pcost);
    k_scan<<<256, 256, 0, stream>>>(pcost, costP, PR, PRm, out);
    k_main<<<516, 256, 0, stream>>>(feat, w1, endn,
                                    costP, PR, PRm, startn, distQ, part);
    k_merge<<<256, 256, 0, stream>>>(feat, b1, w2, b2, dlt, gmm, bta, endn,
                                     distQ, part, out);
}